// Round 1
// baseline (602.732 us; speedup 1.0000x reference)
//
#include <hip/hip_runtime.h>

typedef __bf16 bf16_t;
typedef __attribute__((ext_vector_type(8))) __bf16 bf16x8;
typedef __attribute__((ext_vector_type(4))) float f32x4;

#define M_DIM 8192   // BSZ*SEQ
#define N_DIM 4096   // OUT_DIM
#define K_DIM 4096   // IN_DIM
#define R_DIM 64     // total rank

// ---------------- kernel 1: x fp32 -> bf16 ----------------
__global__ __launch_bounds__(256) void cvt_x(const float* __restrict__ in,
                                             bf16_t* __restrict__ out) {
    size_t i = ((size_t)blockIdx.x * 256 + threadIdx.x) * 8;
    float4 a = *(const float4*)(in + i);
    float4 b = *(const float4*)(in + i + 4);
    bf16x8 v;
    v[0] = (bf16_t)a.x; v[1] = (bf16_t)a.y; v[2] = (bf16_t)a.z; v[3] = (bf16_t)a.w;
    v[4] = (bf16_t)b.x; v[5] = (bf16_t)b.y; v[6] = (bf16_t)b.z; v[7] = (bf16_t)b.w;
    *(bf16x8*)(out + i) = v;
}

// ------- kernel 2: Weff[o][i] = bf16(W[o][i] + sum_r (2*B[o][r])*A[r][i]) -------
__global__ __launch_bounds__(256) void build_weff(const float* __restrict__ W,
                                                  const float* __restrict__ A,
                                                  const float* __restrict__ Bl,
                                                  bf16_t* __restrict__ out) {
    const int i  = blockIdx.x * 256 + threadIdx.x;
    const int o0 = blockIdx.y * 16;

    float acc[16];
#pragma unroll
    for (int j = 0; j < 16; j++) acc[j] = W[(size_t)(o0 + j) * K_DIM + i];

    for (int rh = 0; rh < R_DIM; rh += 16) {   // NOT unrolled: keeps pressure low
        float av[16];
#pragma unroll
        for (int r = 0; r < 16; r++) av[r] = 2.0f * A[(size_t)(rh + r) * K_DIM + i];
#pragma unroll
        for (int j = 0; j < 16; j++) {
#pragma unroll
            for (int r = 0; r < 16; r++)
                acc[j] += Bl[(o0 + j) * R_DIM + rh + r] * av[r];
        }
    }
#pragma unroll
    for (int j = 0; j < 16; j++) out[(size_t)(o0 + j) * K_DIM + i] = (bf16_t)acc[j];
}

// ---------------- kernel 3: C[M][N] = Xb[M][K] * Weff[N][K]^T ----------------
// 256x256 tile, BK=64, 8 waves (2x4), deep pipeline:
//   raw s_barrier (no vmcnt drain) + counted s_waitcnt vmcnt(4).
// LDS [buf][khalf][256 rows][32 k] bf16; 16B chunk c of a row holds global
// chunk c ^ ((row>>1)&3)  (both-sides swizzle: pre-swizzled global source for
// global_load_lds, swizzled ds_read_b128 on consumption).
//
// vmcnt ledger (per-wave issue order, 2 loads per unit):
//   ... [t A-k1]@(t-1.P3) [t B-k1]@(t-1.P4) [t+1 A-k0]@(t.P1) [t+1 B-k0]@(t.P2)
//       [t+1 A-k1]@(t.P3) [t+1 B-k1]@(t.P4) ...
//   P2-end vmcnt(4): newest 4 = {A-k0,B-k0}(t+1)  => {A-k1,B-k1}(t) resident
//       (needed by P3/P4 reads, which occur after P2's trailing barrier).
//   P4-end vmcnt(4): newest 4 = {A-k1,B-k1}(t+1)  => {A-k0,B-k0}(t+1) resident
//       (needed by next tile's P1/P2 reads).
//   Last tile: no prefetch, P2 uses vmcnt(0).
// WAR: unit staged at t.Px overwrites tile t-1 data last read (and lgkm-drained
// by its consuming MFMA) before t-1.P4's trailing barrier, which every wave has
// crossed before issuing t.Px stages.
#define BM 256
#define BN 256
#define BK 64
#define NT (K_DIM / BK)

#define GLDS(gp, lp) __builtin_amdgcn_global_load_lds(                       \
    (__attribute__((address_space(1))) void*)(gp),                           \
    (__attribute__((address_space(3))) void*)(lp), 16, 0, 0)

#define SBAR() __builtin_amdgcn_s_barrier()
#define WAITV(n) asm volatile("s_waitcnt vmcnt(" #n ")" ::: "memory")

#define READ_A(khp, mbase)                                                   \
    _Pragma("unroll")                                                        \
    for (int mf = 0; mf < 4; ++mf)                                           \
        afr[mf] = *(const bf16x8*)((khp) + aoff[(mbase) + mf]);

#define READ_B(khp)                                                          \
    _Pragma("unroll")                                                        \
    for (int nf = 0; nf < 4; ++nf)                                           \
        bfr[nf] = *(const bf16x8*)((khp) + boff[nf]);

#define MFMA_HALF(mbase)                                                     \
    __builtin_amdgcn_s_setprio(1);                                           \
    _Pragma("unroll")                                                        \
    for (int mf = 0; mf < 4; ++mf)                                           \
        _Pragma("unroll")                                                    \
        for (int nf = 0; nf < 4; ++nf)                                       \
            acc[(mbase) + mf][nf] = __builtin_amdgcn_mfma_f32_16x16x32_bf16( \
                afr[mf], bfr[nf], acc[(mbase) + mf][nf], 0, 0, 0);           \
    __builtin_amdgcn_s_setprio(0);

// stage one k-half unit (256 rows x 32 k) of A or B: 2 x global_load_lds(16B)
// per thread; LDS dest linear (wave-uniform base + lane*16), source chunk
// pre-swizzled so LDS[row][c] = global chunk c ^ ((row>>1)&3).
__device__ __forceinline__ void stage_unit(const bf16_t* __restrict__ src,
                                           int row0, int kb, bf16_t* ldsb,
                                           int wave, int srow, int sc) {
#pragma unroll
    for (int j = 0; j < 2; ++j) {
        const int g  = wave * 2 + j;          // 16-row group, wave-uniform
        const int r  = g * 16 + srow;
        const int cs = sc ^ ((r >> 1) & 3);   // source 16B chunk (involution)
        GLDS(src + (size_t)(row0 + r) * K_DIM + kb + cs * 8, ldsb + g * 512);
    }
}

__global__ __launch_bounds__(512, 2) void gemm_bf16(const bf16_t* __restrict__ Ax,
                                                    const bf16_t* __restrict__ Bw,
                                                    float* __restrict__ C) {
    __shared__ __attribute__((aligned(16))) bf16_t Ash[2][2][BM][32];
    __shared__ __attribute__((aligned(16))) bf16_t Bsh[2][2][BN][32];

    const int tid  = threadIdx.x;
    const int wave = tid >> 6;
    const int lane = tid & 63;
    const int m16  = lane & 15;
    const int quad = lane >> 4;
    const int wm   = wave >> 2;   // 0..1 -> 128-row half
    const int wn   = wave & 3;    // 0..3 -> 64-col quarter

    // XCD-aware bijective swizzle (512 blocks, 512 % 8 == 0)
    const int fid = blockIdx.y * 16 + blockIdx.x;
    const int swz = (fid & 7) * 64 + (fid >> 3);
    const int m0  = (swz >> 4) * BM;
    const int n0  = (swz & 15) * BN;

    // staging lane geometry: row = group*16 + (lane>>2), chunk = lane&3
    const int srow = lane >> 2;
    const int sc   = lane & 3;

    // consumption offsets (elements) into a [256][32] k-half
    int aoff[8], boff[4];
#pragma unroll
    for (int mf = 0; mf < 8; ++mf) {
        const int mr = wm * 128 + mf * 16 + m16;
        aoff[mf] = mr * 32 + ((quad ^ ((mr >> 1) & 3)) << 3);
    }
#pragma unroll
    for (int nf = 0; nf < 4; ++nf) {
        const int nr = wn * 64 + nf * 16 + m16;
        boff[nf] = nr * 32 + ((quad ^ ((nr >> 1) & 3)) << 3);
    }

    f32x4 acc[8][4] = {};

    // prologue: stage tile 0 (A-k0, B-k0, A-k1, B-k1) into buf 0
    stage_unit(Ax, m0, 0,  &Ash[0][0][0][0], wave, srow, sc);
    stage_unit(Bw, n0, 0,  &Bsh[0][0][0][0], wave, srow, sc);
    stage_unit(Ax, m0, 32, &Ash[0][1][0][0], wave, srow, sc);
    stage_unit(Bw, n0, 32, &Bsh[0][1][0][0], wave, srow, sc);
    WAITV(4);          // k0 pair resident; k1 pair may still fly (P2 covers it)
    SBAR();

#pragma unroll 2
    for (int t = 0; t < NT; ++t) {
        const int  cur = t & 1, nxt = cur ^ 1;
        const int  kn  = (t + 1) * BK;
        const bool pf  = (t + 1) < NT;
        const bf16_t* A0 = &Ash[cur][0][0][0];
        const bf16_t* A1 = &Ash[cur][1][0][0];
        const bf16_t* B0 = &Bsh[cur][0][0][0];
        const bf16_t* B1 = &Bsh[cur][1][0][0];
        bf16x8 afr[4], bfr[4];

        // ---- P1: mf0-3 x k0 ; prefetch A-k0(t+1) ----
        READ_B(B0);
        READ_A(A0, 0);
        if (pf) stage_unit(Ax, m0, kn, &Ash[nxt][0][0][0], wave, srow, sc);
        SBAR();
        MFMA_HALF(0);
        SBAR();

        // ---- P2: mf4-7 x k0 ; prefetch B-k0(t+1) ; ensure k1(t) resident ----
        READ_A(A0, 4);
        if (pf) stage_unit(Bw, n0, kn, &Bsh[nxt][0][0][0], wave, srow, sc);
        SBAR();
        MFMA_HALF(4);
        if (pf) { WAITV(4); } else { WAITV(0); }
        SBAR();

        // ---- P3: mf0-3 x k1 ; prefetch A-k1(t+1) ----
        READ_B(B1);
        READ_A(A1, 0);
        if (pf) stage_unit(Ax, m0, kn + 32, &Ash[nxt][1][0][0], wave, srow, sc);
        SBAR();
        MFMA_HALF(0);
        SBAR();

        // ---- P4: mf4-7 x k1 ; prefetch B-k1(t+1) ; ensure k0(t+1) resident ----
        READ_A(A1, 4);
        if (pf) stage_unit(Bw, n0, kn + 32, &Bsh[nxt][1][0][0], wave, srow, sc);
        SBAR();
        MFMA_HALF(4);
        if (pf) { WAITV(4); }
        SBAR();
    }

    // epilogue: C/D layout col = lane&15, row = quad*4 + reg
#pragma unroll
    for (int mf = 0; mf < 8; ++mf) {
#pragma unroll
        for (int i = 0; i < 4; ++i) {
            const int gm = m0 + wm * 128 + mf * 16 + quad * 4 + i;
            float* crow = C + (size_t)gm * N_DIM + n0 + wn * 64 + m16;
#pragma unroll
            for (int nf = 0; nf < 4; ++nf)
                crow[nf * 16] = acc[mf][nf][i];
        }
    }
}

extern "C" void kernel_launch(void* const* d_in, const int* in_sizes, int n_in,
                              void* d_out, int out_size, void* d_ws, size_t ws_size,
                              hipStream_t stream) {
    const float* x  = (const float*)d_in[0];
    const float* W  = (const float*)d_in[1];
    const float* La = (const float*)d_in[2];
    const float* Lb = (const float*)d_in[3];
    float* out = (float*)d_out;

    // workspace: xb (64 MiB) | Weff (32 MiB)
    bf16_t* xb = (bf16_t*)d_ws;
    bf16_t* wf = (bf16_t*)((char*)d_ws + (size_t)M_DIM * K_DIM * sizeof(bf16_t));

    cvt_x<<<(M_DIM * K_DIM) / (256 * 8), 256, 0, stream>>>(x, xb);
    build_weff<<<dim3(K_DIM / 256, N_DIM / 16), 256, 0, stream>>>(W, La, Lb, wf);
    gemm_bf16<<<dim3(N_DIM / BN, M_DIM / BM), 512, 0, stream>>>(xb, wf, out);
}